// Round 12
// baseline (404.825 us; speedup 1.0000x reference)
//
#include <hip/hip_runtime.h>
#include <hip/hip_bf16.h>
#include <hip/hip_fp16.h>
#include <cstddef>

#define N_NODES 100000
#define F_IN    512
#define HID     64
#define NCLS    40

#define BUCK_SZ   4
#define BUCK_CAP  128                      // entries per bucket window (Poisson(64) tail ~1e-11)
#define NBUCK     (N_NODES / BUCK_SZ)      // 25000, exact
#define SRC_MASK  0x1FFFF                  // 17 bits
#define CUR_PAD   16                       // ints: one cursor per 64B line

#define NPART       8
#define PART_NODES  12500                  // 100000/8, divisible by BUCK_SZ
#define PART_BLOCKS 256

using half8 = __attribute__((ext_vector_type(8))) _Float16;
using f32x4 = __attribute__((ext_vector_type(4))) float;

// ---------- utility ----------
__global__ void zero_kernel(int* __restrict__ p, int n) {
    int i = blockIdx.x * blockDim.x + threadIdx.x;
    if (i < n) p[i] = 0;
}

// ---------- degree count, XCD-partitioned ----------
__global__ __launch_bounds__(256) void count_part_kernel(const int* __restrict__ dst,
                                                         int* __restrict__ cnt, int E) {
    const int p  = blockIdx.x & (NPART - 1);
    const int bi = blockIdx.x >> 3;
    const int nb = gridDim.x >> 3;
    const int lo = p * PART_NODES, hi = lo + PART_NODES;
    for (int e = bi * 256 + (int)threadIdx.x; e < E; e += nb * 256) {
        int d = dst[e];
        if (d >= lo && d < hi) atomicAdd(&cnt[d], 1);
    }
}

__global__ void make_dinv_kernel(const int* __restrict__ cnt, float* __restrict__ dinv, int n) {
    int i = blockIdx.x * blockDim.x + threadIdx.x;
    if (i < n) dinv[i] = rsqrtf((float)(cnt[i] + 1));   // +1 self-loop
}

// ---------- XCD-partitioned scatter into fixed-capacity dst-buckets ----------
// entry = { src | dst_local<<17 , norm fp32 }; window base = b*BUCK_CAP (no scan).
__global__ __launch_bounds__(256) void scatter_part_kernel(const int* __restrict__ src,
                                                           const int* __restrict__ dst,
                                                           const float* __restrict__ dinv,
                                                           int* __restrict__ bcur,
                                                           uint2* __restrict__ ebuf,
                                                           int E) {
    const int p  = blockIdx.x & (NPART - 1);
    const int bi = blockIdx.x >> 3;
    const int nb = gridDim.x >> 3;
    const int lo = p * PART_NODES, hi = lo + PART_NODES;
    for (int e = bi * 256 + (int)threadIdx.x; e < E; e += nb * 256) {
        int d = dst[e];
        if (d >= lo && d < hi) {
            int s = src[e];
            int b = d >> 2;                       // BUCK_SZ = 4
            int pos = atomicAdd(&bcur[b * CUR_PAD], 1);
            if (pos < BUCK_CAP) {
                float nm = dinv[s] * dinv[d];
                ebuf[(size_t)b * BUCK_CAP + pos] =
                    make_uint2((unsigned int)s | ((unsigned int)(d & 3) << 17),
                               __float_as_uint(nm));
            }
        }
    }
}

// ---------- GEMM1 (MFMA fp16): H1 = X (Mx512) @ W1 (512x64), fp16 out ----------
__global__ __launch_bounds__(256) void gemm1_mfma_kernel(const float* __restrict__ X,
                                                         const float* __restrict__ W,
                                                         __half* __restrict__ H, int M) {
    __shared__ _Float16 As[4][64][8];   // 4 KB
    __shared__ _Float16 Bs[4][64][8];   // 4 KB

    const int tid  = threadIdx.x;
    const int lane = tid & 63;
    const int w    = tid >> 6;
    const int l15  = lane & 15;
    const int kg   = lane >> 4;
    const int rowBase = blockIdx.x * 64;

    f32x4 acc[4] = {};

    for (int kt = 0; kt < F_IN; kt += 32) {
        #pragma unroll
        for (int p = 0; p < 2; ++p) {
            int idx = tid * 2 + p;           // 0..511
            int r = idx >> 3, k4 = idx & 7;  // row, k-quad
            int gr = rowBase + r; if (gr >= M) gr = M - 1;
            const float4 v = *reinterpret_cast<const float4*>(
                &X[(size_t)gr * F_IN + kt + k4 * 4]);
            _Float16* dstp = &As[k4 >> 1][r][(k4 & 1) * 4];
            dstp[0] = (_Float16)v.x; dstp[1] = (_Float16)v.y;
            dstp[2] = (_Float16)v.z; dstp[3] = (_Float16)v.w;
        }
        #pragma unroll
        for (int p = 0; p < 2; ++p) {
            int idx = tid * 2 + p;           // 0..511
            int k = idx >> 4, c4 = idx & 15;
            const float4 v = *reinterpret_cast<const float4*>(
                &W[(size_t)(kt + k) * HID + c4 * 4]);
            int kgg = k >> 3, j = k & 7;
            Bs[kgg][c4 * 4 + 0][j] = (_Float16)v.x;
            Bs[kgg][c4 * 4 + 1][j] = (_Float16)v.y;
            Bs[kgg][c4 * 4 + 2][j] = (_Float16)v.z;
            Bs[kgg][c4 * 4 + 3][j] = (_Float16)v.w;
        }
        __syncthreads();

        const half8 a = *reinterpret_cast<const half8*>(&As[kg][w * 16 + l15][0]);
        #pragma unroll
        for (int ct = 0; ct < 4; ++ct) {
            const half8 b = *reinterpret_cast<const half8*>(&Bs[kg][ct * 16 + l15][0]);
            acc[ct] = __builtin_amdgcn_mfma_f32_16x16x32_f16(a, b, acc[ct], 0, 0, 0);
        }
        __syncthreads();
    }

    #pragma unroll
    for (int ct = 0; ct < 4; ++ct) {
        #pragma unroll
        for (int r = 0; r < 4; ++r) {
            int grow = rowBase + w * 16 + kg * 4 + r;
            if (grow < M) H[(size_t)grow * HID + ct * 16 + l15] = __float2half(acc[ct][r]);
        }
    }
}

// ---------- agg pass 1: z = relu(A*h + b1); one wave per 4-node bucket ----------
__global__ __launch_bounds__(256) void agg1_bucket_kernel(const __half* __restrict__ h,
                                                          const uint2* __restrict__ ebuf,
                                                          const int* __restrict__ bcur,
                                                          const float* __restrict__ dinv,
                                                          const float* __restrict__ b1,
                                                          __half* __restrict__ z) {
    const int lane = threadIdx.x & 63;
    const int b = blockIdx.x * 4 + (threadIdx.x >> 6);   // bucket id < 25000
    const int n0 = b * BUCK_SZ;

    float acc[BUCK_SZ];
    #pragma unroll
    for (int k = 0; k < BUCK_SZ; ++k) {
        float dv = dinv[n0 + k];
        acc[k] = __half2float(h[(size_t)(n0 + k) * HID + lane]) * dv * dv;  // self-loop
    }

    const int cnt = min(bcur[b * CUR_PAD], BUCK_CAP);
    const uint2* win = &ebuf[(size_t)b * BUCK_CAP];

    for (int e = 0; e < cnt; ) {
        uint2 ent = make_uint2(0u, 0u);                 // pad: nm = 0
        if (e + lane < cnt) ent = win[e + lane];
        const int c = min(64, cnt - e);
        int j = 0;
        for (; j + 4 <= c; j += 4) {
            #pragma unroll
            for (int q = 0; q < 4; ++q) {
                unsigned int sw = __shfl(ent.x, j + q);
                float nm = __int_as_float(__shfl((int)ent.y, j + q));
                int s   = (int)(sw & SRC_MASK);
                int loc = (int)(sw >> 17);
                float v = __half2float(h[(size_t)s * HID + lane]);
                #pragma unroll
                for (int k = 0; k < BUCK_SZ; ++k)
                    acc[k] = fmaf(v, (loc == k) ? nm : 0.0f, acc[k]);
            }
        }
        for (; j < c; ++j) {
            unsigned int sw = __shfl(ent.x, j);
            float nm = __int_as_float(__shfl((int)ent.y, j));
            int s   = (int)(sw & SRC_MASK);
            int loc = (int)(sw >> 17);
            float v = __half2float(h[(size_t)s * HID + lane]);
            #pragma unroll
            for (int k = 0; k < BUCK_SZ; ++k)
                acc[k] = fmaf(v, (loc == k) ? nm : 0.0f, acc[k]);
        }
        e += c;
    }

    const float bb = b1[lane];
    #pragma unroll
    for (int k = 0; k < BUCK_SZ; ++k)
        z[(size_t)(n0 + k) * HID + lane] = __float2half(fmaxf(acc[k] + bb, 0.0f));
}

// ---------- GEMM2: h2 = z (Mx64 fp16) @ W2 (64x40) -> fp16, STRIDE 64 ----------
__global__ __launch_bounds__(256) void gemm2_kernel(const __half* __restrict__ z,
                                                    const float* __restrict__ W2,
                                                    __half* __restrict__ h2, int M) {
    __shared__ float W2s[HID * NCLS];   // 10.24 KB
    __shared__ float zs[64 * HID];      // 16 KB

    const int tid = threadIdx.x;
    const int rowBase = blockIdx.x * 64;

    for (int i = tid; i < HID * NCLS; i += 256) W2s[i] = W2[i];

    #pragma unroll
    for (int p = 0; p < 2; ++p) {
        int o = tid * 2 + p;            // 0..511 chunks of 8 halves
        int r = o >> 3, c8 = o & 7;
        int gr = rowBase + r;
        float4 raw = make_float4(0.f, 0.f, 0.f, 0.f);
        if (gr < M) raw = *reinterpret_cast<const float4*>(&z[(size_t)gr * HID + c8 * 8]);
        const __half2* hp = reinterpret_cast<const __half2*>(&raw);
        #pragma unroll
        for (int q = 0; q < 4; ++q) {
            float2 f = __half22float2(hp[q]);
            zs[r * HID + c8 * 8 + q * 2]     = f.x;
            zs[r * HID + c8 * 8 + q * 2 + 1] = f.y;
        }
    }
    __syncthreads();

    #pragma unroll
    for (int p = 0; p < 10; ++p) {
        int o = p * 256 + tid;          // 0..2559 = 64 rows x 40 cols
        int r = o / NCLS, j = o - r * NCLS;
        float s = 0.f;
        #pragma unroll
        for (int k = 0; k < HID; ++k) s = fmaf(zs[r * HID + k], W2s[k * NCLS + j], s);
        int gr = rowBase + r;
        if (gr < M) h2[(size_t)gr * 64 + j] = __float2half(s);   // stride 64 (aligned rows)
    }
}

// ---------- agg pass 2 + b2 + log_softmax; one wave per 4-node bucket ----------
__global__ __launch_bounds__(256) void agg2_bucket_lsm_kernel(const __half* __restrict__ h2,
                                                              const uint2* __restrict__ ebuf,
                                                              const int* __restrict__ bcur,
                                                              const float* __restrict__ dinv,
                                                              const float* __restrict__ b2,
                                                              float* __restrict__ out) {
    const int lane = threadIdx.x & 63;
    const int b = blockIdx.x * 4 + (threadIdx.x >> 6);
    const int n0 = b * BUCK_SZ;
    const bool act = (lane < NCLS);

    float acc[BUCK_SZ];
    #pragma unroll
    for (int k = 0; k < BUCK_SZ; ++k) {
        float dv = dinv[n0 + k];
        acc[k] = act ? __half2float(h2[(size_t)(n0 + k) * 64 + lane]) * dv * dv : 0.f;
    }

    const int cnt = min(bcur[b * CUR_PAD], BUCK_CAP);
    const uint2* win = &ebuf[(size_t)b * BUCK_CAP];

    for (int e = 0; e < cnt; ) {
        uint2 ent = make_uint2(0u, 0u);
        if (e + lane < cnt) ent = win[e + lane];
        const int c = min(64, cnt - e);
        int j = 0;
        for (; j + 4 <= c; j += 4) {
            #pragma unroll
            for (int q = 0; q < 4; ++q) {
                unsigned int sw = __shfl(ent.x, j + q);
                float nm = __int_as_float(__shfl((int)ent.y, j + q));
                int s   = (int)(sw & SRC_MASK);
                int loc = (int)(sw >> 17);
                float v = act ? __half2float(h2[(size_t)s * 64 + lane]) : 0.f;
                #pragma unroll
                for (int k = 0; k < BUCK_SZ; ++k)
                    acc[k] = fmaf(v, (loc == k) ? nm : 0.0f, acc[k]);
            }
        }
        for (; j < c; ++j) {
            unsigned int sw = __shfl(ent.x, j);
            float nm = __int_as_float(__shfl((int)ent.y, j));
            int s   = (int)(sw & SRC_MASK);
            int loc = (int)(sw >> 17);
            float v = act ? __half2float(h2[(size_t)s * 64 + lane]) : 0.f;
            #pragma unroll
            for (int k = 0; k < BUCK_SZ; ++k)
                acc[k] = fmaf(v, (loc == k) ? nm : 0.0f, acc[k]);
        }
        e += c;
    }

    const float bb = act ? b2[lane] : 0.f;
    #pragma unroll
    for (int k = 0; k < BUCK_SZ; ++k) {
        float logit = act ? (acc[k] + bb) : -1e30f;
        float m = logit;
        #pragma unroll
        for (int o = 32; o >= 1; o >>= 1) m = fmaxf(m, __shfl_xor(m, o));
        float ex = act ? __expf(logit - m) : 0.f;
        float sm = ex;
        #pragma unroll
        for (int o = 32; o >= 1; o >>= 1) sm += __shfl_xor(sm, o);
        float res = logit - m - __logf(sm);
        if (act) out[(size_t)(n0 + k) * NCLS + lane] = res;
    }
}

extern "C" void kernel_launch(void* const* d_in, const int* in_sizes, int n_in,
                              void* d_out, int out_size, void* d_ws, size_t ws_size,
                              hipStream_t stream) {
    const float* x  = (const float*)d_in[0];
    const int*   ei = (const int*)d_in[1];
    const float* W1 = (const float*)d_in[2];
    const float* b1 = (const float*)d_in[3];
    const float* W2 = (const float*)d_in[4];
    const float* b2 = (const float*)d_in[5];
    float* out = (float*)d_out;

    const int M = N_NODES;
    const int E = in_sizes[1] / 2;
    const int* src = ei;
    const int* dst = ei + E;

    // ---- workspace layout (peak 66.4 MB; ws_size ≈ 800 MB per fill counters) ----
    char* ws = (char*)d_ws;
    int*    cnt  = (int*)   (ws + 0);            // 400 KB
    int*    bcur = (int*)   (ws + 409600);       // 25000*64 B = 1.6 MB  (zeroed with cnt)
    float*  dinv = (float*) (ws + 2009600);      // 400 KB
    uint2*  ebuf = (uint2*) (ws + 2409600);      // 25000*128*8 = 25.6 MB -> 28,009,600
    __half* h1   = (__half*)(ws + 28009600);     // 12.8 MB -> 40,809,600
    __half* z    = (__half*)(ws + 40809600);     // 12.8 MB -> 53,609,600
    __half* h2   = (__half*)(ws + 53609600);     // stride-64: 12.8 MB -> 66,409,600

    // zero cnt + bcur (contiguous 2,009,600 bytes = 502,400 ints)
    zero_kernel<<<(502400 + 255) / 256, 256, 0, stream>>>(cnt, 502400);
    count_part_kernel<<<NPART * PART_BLOCKS, 256, 0, stream>>>(dst, cnt, E);
    make_dinv_kernel<<<(M + 255) / 256, 256, 0, stream>>>(cnt, dinv, M);

    scatter_part_kernel<<<NPART * PART_BLOCKS, 256, 0, stream>>>(src, dst, dinv, bcur, ebuf, E);

    gemm1_mfma_kernel<<<(M + 63) / 64, 256, 0, stream>>>(x, W1, h1, M);

    agg1_bucket_kernel<<<NBUCK / 4, 256, 0, stream>>>(h1, ebuf, bcur, dinv, b1, z);

    gemm2_kernel<<<(M + 63) / 64, 256, 0, stream>>>(z, W2, h2, M);
    agg2_bucket_lsm_kernel<<<NBUCK / 4, 256, 0, stream>>>(h2, ebuf, bcur, dinv, b2, out);
}

// Round 13
// 295.544 us; speedup vs baseline: 1.3698x; 1.3698x over previous
//
#include <hip/hip_runtime.h>
#include <hip/hip_bf16.h>
#include <hip/hip_fp16.h>
#include <cstddef>

#define N_NODES 100000
#define F_IN    512
#define HID     64
#define NCLS    40

#define CAP       64                       // per-node window capacity (P(deg>64)~2e-18)
#define CUR_PAD   16                       // ints: one cursor per 64B line

#define NPART       8
#define PART_NODES  12500                  // 100000/8
#define PART_BLOCKS 256

using half8 = __attribute__((ext_vector_type(8))) _Float16;
using f32x4 = __attribute__((ext_vector_type(4))) float;

// ---------- utility ----------
__global__ void zero_kernel(int* __restrict__ p, int n) {
    int i = blockIdx.x * blockDim.x + threadIdx.x;
    if (i < n) p[i] = 0;
}

// ---------- XCD-partitioned scatter into per-node fixed windows ----------
// partition p = blockIdx & 7 -> XCD p (round-robin dispatch); a node's window
// lines are written only from its partition's XCD -> lines fill in local L2.
__global__ __launch_bounds__(256) void scatter_part_kernel(const int* __restrict__ src,
                                                           const int* __restrict__ dst,
                                                           int* __restrict__ cur,
                                                           int* __restrict__ ebuf, int E) {
    const int p  = blockIdx.x & (NPART - 1);
    const int bi = blockIdx.x >> 3;
    const int nb = gridDim.x >> 3;
    const int lo = p * PART_NODES, hi = lo + PART_NODES;
    for (int e = bi * 256 + (int)threadIdx.x; e < E; e += nb * 256) {
        int d = dst[e];
        if (d >= lo && d < hi) {
            int pos = atomicAdd(&cur[d * CUR_PAD], 1);
            if (pos < CAP) ebuf[(size_t)d * CAP + pos] = src[e];
        }
    }
}

// ---------- dinv from cursor counts ----------
__global__ void make_dinv_kernel(const int* __restrict__ cur, float* __restrict__ dinv, int n) {
    int i = blockIdx.x * blockDim.x + threadIdx.x;
    if (i < n) dinv[i] = rsqrtf((float)(cur[i * CUR_PAD] + 1));   // +1 self-loop
}

// ---------- GEMM1 (MFMA fp16): H1 = X (Mx512) @ W1 (512x64), fp16 out ----------
__global__ __launch_bounds__(256) void gemm1_mfma_kernel(const float* __restrict__ X,
                                                         const float* __restrict__ W,
                                                         __half* __restrict__ H, int M) {
    __shared__ _Float16 As[4][64][8];   // 4 KB
    __shared__ _Float16 Bs[4][64][8];   // 4 KB

    const int tid  = threadIdx.x;
    const int lane = tid & 63;
    const int w    = tid >> 6;
    const int l15  = lane & 15;
    const int kg   = lane >> 4;
    const int rowBase = blockIdx.x * 64;

    f32x4 acc[4] = {};

    for (int kt = 0; kt < F_IN; kt += 32) {
        #pragma unroll
        for (int p = 0; p < 2; ++p) {
            int idx = tid * 2 + p;           // 0..511
            int r = idx >> 3, k4 = idx & 7;  // row, k-quad
            int gr = rowBase + r; if (gr >= M) gr = M - 1;
            const float4 v = *reinterpret_cast<const float4*>(
                &X[(size_t)gr * F_IN + kt + k4 * 4]);
            _Float16* dstp = &As[k4 >> 1][r][(k4 & 1) * 4];
            dstp[0] = (_Float16)v.x; dstp[1] = (_Float16)v.y;
            dstp[2] = (_Float16)v.z; dstp[3] = (_Float16)v.w;
        }
        #pragma unroll
        for (int p = 0; p < 2; ++p) {
            int idx = tid * 2 + p;           // 0..511
            int k = idx >> 4, c4 = idx & 15;
            const float4 v = *reinterpret_cast<const float4*>(
                &W[(size_t)(kt + k) * HID + c4 * 4]);
            int kgg = k >> 3, j = k & 7;
            Bs[kgg][c4 * 4 + 0][j] = (_Float16)v.x;
            Bs[kgg][c4 * 4 + 1][j] = (_Float16)v.y;
            Bs[kgg][c4 * 4 + 2][j] = (_Float16)v.z;
            Bs[kgg][c4 * 4 + 3][j] = (_Float16)v.w;
        }
        __syncthreads();

        const half8 a = *reinterpret_cast<const half8*>(&As[kg][w * 16 + l15][0]);
        #pragma unroll
        for (int ct = 0; ct < 4; ++ct) {
            const half8 b = *reinterpret_cast<const half8*>(&Bs[kg][ct * 16 + l15][0]);
            acc[ct] = __builtin_amdgcn_mfma_f32_16x16x32_f16(a, b, acc[ct], 0, 0, 0);
        }
        __syncthreads();
    }

    #pragma unroll
    for (int ct = 0; ct < 4; ++ct) {
        #pragma unroll
        for (int r = 0; r < 4; ++r) {
            int grow = rowBase + w * 16 + kg * 4 + r;
            if (grow < M) H[(size_t)grow * HID + ct * 16 + l15] = __float2half(acc[ct][r]);
        }
    }
}

// ---------- agg pass 1: z = relu(A*h + b1); one wave per node, single batch ----------
__global__ __launch_bounds__(256) void agg1_kernel(const __half* __restrict__ h,
                                                   const int* __restrict__ ebuf,
                                                   const int* __restrict__ cur,
                                                   const float* __restrict__ dinv,
                                                   const float* __restrict__ b1,
                                                   __half* __restrict__ z, int M) {
    const int lane = threadIdx.x & 63;
    const int n = blockIdx.x * 4 + (threadIdx.x >> 6);
    if (n >= M) return;

    const float di = dinv[n];
    float acc = __half2float(h[(size_t)n * HID + lane]) * di * di;   // self-loop

    const int cnt = min(cur[n * CUR_PAD], CAP);
    const int* win = &ebuf[(size_t)n * CAP];

    int   s  = 0;
    float nm = 0.f;
    if (lane < cnt) {
        s  = win[lane];
        nm = dinv[s] * di;
    }
    int j = 0;
    for (; j + 4 <= cnt; j += 4) {
        int sa = __shfl(s, j);
        int sb = __shfl(s, j + 1);
        int sc = __shfl(s, j + 2);
        int sd = __shfl(s, j + 3);
        float na = __shfl(nm, j);
        float nb = __shfl(nm, j + 1);
        float nc = __shfl(nm, j + 2);
        float nd = __shfl(nm, j + 3);
        float va = __half2float(h[(size_t)sa * HID + lane]);
        float vb = __half2float(h[(size_t)sb * HID + lane]);
        float vc = __half2float(h[(size_t)sc * HID + lane]);
        float vd = __half2float(h[(size_t)sd * HID + lane]);
        acc = fmaf(va, na, acc);
        acc = fmaf(vb, nb, acc);
        acc = fmaf(vc, nc, acc);
        acc = fmaf(vd, nd, acc);
    }
    for (; j < cnt; ++j) {
        int sj = __shfl(s, j);
        float nj = __shfl(nm, j);
        acc = fmaf(__half2float(h[(size_t)sj * HID + lane]), nj, acc);
    }

    acc = fmaxf(acc + b1[lane], 0.0f);
    z[(size_t)n * HID + lane] = __float2half(acc);
}

// ---------- GEMM2: h2 = z (Mx64 fp16) @ W2 (64x40) -> fp16, STRIDE 64 ----------
__global__ __launch_bounds__(256) void gemm2_kernel(const __half* __restrict__ z,
                                                    const float* __restrict__ W2,
                                                    __half* __restrict__ h2, int M) {
    __shared__ float W2s[HID * NCLS];   // 10.24 KB
    __shared__ float zs[64 * HID];      // 16 KB

    const int tid = threadIdx.x;
    const int rowBase = blockIdx.x * 64;

    for (int i = tid; i < HID * NCLS; i += 256) W2s[i] = W2[i];

    #pragma unroll
    for (int p = 0; p < 2; ++p) {
        int o = tid * 2 + p;            // 0..511 chunks of 8 halves
        int r = o >> 3, c8 = o & 7;
        int gr = rowBase + r;
        float4 raw = make_float4(0.f, 0.f, 0.f, 0.f);
        if (gr < M) raw = *reinterpret_cast<const float4*>(&z[(size_t)gr * HID + c8 * 8]);
        const __half2* hp = reinterpret_cast<const __half2*>(&raw);
        #pragma unroll
        for (int q = 0; q < 4; ++q) {
            float2 f = __half22float2(hp[q]);
            zs[r * HID + c8 * 8 + q * 2]     = f.x;
            zs[r * HID + c8 * 8 + q * 2 + 1] = f.y;
        }
    }
    __syncthreads();

    #pragma unroll
    for (int p = 0; p < 10; ++p) {
        int o = p * 256 + tid;          // 0..2559 = 64 rows x 40 cols
        int r = o / NCLS, j = o - r * NCLS;
        float s = 0.f;
        #pragma unroll
        for (int k = 0; k < HID; ++k) s = fmaf(zs[r * HID + k], W2s[k * NCLS + j], s);
        int gr = rowBase + r;
        if (gr < M) h2[(size_t)gr * 64 + j] = __float2half(s);   // stride 64 (aligned rows)
    }
}

// ---------- agg pass 2 + b2 + log_softmax; one wave per node, single batch ----------
__global__ __launch_bounds__(256) void agg2_lsm_kernel(const __half* __restrict__ h2,
                                                       const int* __restrict__ ebuf,
                                                       const int* __restrict__ cur,
                                                       const float* __restrict__ dinv,
                                                       const float* __restrict__ b2,
                                                       float* __restrict__ out, int M) {
    const int lane = threadIdx.x & 63;
    const int n = blockIdx.x * 4 + (threadIdx.x >> 6);
    if (n >= M) return;

    const bool act = (lane < NCLS);
    const float di = dinv[n];
    float acc = act ? __half2float(h2[(size_t)n * 64 + lane]) * di * di : 0.f;  // self-loop

    const int cnt = min(cur[n * CUR_PAD], CAP);
    const int* win = &ebuf[(size_t)n * CAP];

    int   s  = 0;
    float nm = 0.f;
    if (lane < cnt) {
        s  = win[lane];
        nm = dinv[s] * di;
    }
    int j = 0;
    for (; j + 4 <= cnt; j += 4) {
        int sa = __shfl(s, j);
        int sb = __shfl(s, j + 1);
        int sc = __shfl(s, j + 2);
        int sd = __shfl(s, j + 3);
        float na = __shfl(nm, j);
        float nb = __shfl(nm, j + 1);
        float nc = __shfl(nm, j + 2);
        float nd = __shfl(nm, j + 3);
        if (act) {
            float va = __half2float(h2[(size_t)sa * 64 + lane]);
            float vb = __half2float(h2[(size_t)sb * 64 + lane]);
            float vc = __half2float(h2[(size_t)sc * 64 + lane]);
            float vd = __half2float(h2[(size_t)sd * 64 + lane]);
            acc = fmaf(va, na, acc);
            acc = fmaf(vb, nb, acc);
            acc = fmaf(vc, nc, acc);
            acc = fmaf(vd, nd, acc);
        }
    }
    for (; j < cnt; ++j) {
        int sj = __shfl(s, j);
        float nj = __shfl(nm, j);
        if (act) acc = fmaf(__half2float(h2[(size_t)sj * 64 + lane]), nj, acc);
    }

    float logit = act ? (acc + b2[lane]) : -1e30f;
    float m = logit;
    #pragma unroll
    for (int o = 32; o >= 1; o >>= 1) m = fmaxf(m, __shfl_xor(m, o));
    float ex = act ? __expf(logit - m) : 0.f;
    float sm = ex;
    #pragma unroll
    for (int o = 32; o >= 1; o >>= 1) sm += __shfl_xor(sm, o);
    float res = logit - m - __logf(sm);

    if (act) out[(size_t)n * NCLS + lane] = res;
}

extern "C" void kernel_launch(void* const* d_in, const int* in_sizes, int n_in,
                              void* d_out, int out_size, void* d_ws, size_t ws_size,
                              hipStream_t stream) {
    const float* x  = (const float*)d_in[0];
    const int*   ei = (const int*)d_in[1];
    const float* W1 = (const float*)d_in[2];
    const float* b1 = (const float*)d_in[3];
    const float* W2 = (const float*)d_in[4];
    const float* b2 = (const float*)d_in[5];
    float* out = (float*)d_out;

    const int M = N_NODES;
    const int E = in_sizes[1] / 2;
    const int* src = ei;
    const int* dst = ei + E;

    // ---- workspace layout (peak ~70.8 MB; ws_size ≈ 800 MB per fill counters) ----
    char* ws = (char*)d_ws;
    int*    cur  = (int*)   (ws + 0);            // 100K * 64 B = 6.4 MB (padded cursors)
    float*  dinv = (float*) (ws + 6400000);      // 400 KB
    int*    ebuf = (int*)   (ws + 6800000);      // 100K * 64 * 4 B = 25.6 MB -> 32.4M
    __half* h1   = (__half*)(ws + 32400000);     // 12.8 MB -> 45.2M
    __half* z    = (__half*)(ws + 45200000);     // 12.8 MB -> 58.0M
    __half* h2   = (__half*)(ws + 58000000);     // stride-64: 12.8 MB -> 70.8M

    zero_kernel<<<(M * CUR_PAD + 255) / 256, 256, 0, stream>>>(cur, M * CUR_PAD);

    scatter_part_kernel<<<NPART * PART_BLOCKS, 256, 0, stream>>>(src, dst, cur, ebuf, E);
    make_dinv_kernel<<<(M + 255) / 256, 256, 0, stream>>>(cur, dinv, M);

    gemm1_mfma_kernel<<<(M + 63) / 64, 256, 0, stream>>>(x, W1, h1, M);

    agg1_kernel<<<(M + 3) / 4, 256, 0, stream>>>(h1, ebuf, cur, dinv, b1, z, M);

    gemm2_kernel<<<(M + 63) / 64, 256, 0, stream>>>(z, W2, h2, M);
    agg2_lsm_kernel<<<(M + 3) / 4, 256, 0, stream>>>(h2, ebuf, cur, dinv, b2, out, M);
}

// Round 14
// 294.827 us; speedup vs baseline: 1.3731x; 1.0024x over previous
//
#include <hip/hip_runtime.h>
#include <hip/hip_bf16.h>
#include <hip/hip_fp16.h>
#include <cstddef>

#define N_NODES 100000
#define F_IN    512
#define HID     64
#define NCLS    40

#define CAP       64                       // per-node window capacity (P(deg>64)~2e-18)

#define NPART       8
#define PART_NODES  12500                  // 100000/8
#define PART_BLOCKS 256

using half8 = __attribute__((ext_vector_type(8))) _Float16;
using f32x4 = __attribute__((ext_vector_type(4))) float;

// ---------- utility ----------
__global__ void zero_kernel(int* __restrict__ p, int n) {
    int i = blockIdx.x * blockDim.x + threadIdx.x;
    if (i < n) p[i] = 0;
}

// ---------- XCD-partitioned scatter into per-node fixed windows ----------
// partition p = blockIdx & 7 -> XCD p (round-robin dispatch); a node's window
// lines are written only from its partition's XCD -> lines fill in local L2.
__global__ __launch_bounds__(256) void scatter_part_kernel(const int* __restrict__ src,
                                                           const int* __restrict__ dst,
                                                           int* __restrict__ cur,
                                                           int* __restrict__ ebuf, int E) {
    const int p  = blockIdx.x & (NPART - 1);
    const int bi = blockIdx.x >> 3;
    const int nb = gridDim.x >> 3;
    const int lo = p * PART_NODES, hi = lo + PART_NODES;
    for (int e = bi * 256 + (int)threadIdx.x; e < E; e += nb * 256) {
        int d = dst[e];
        if (d >= lo && d < hi) {
            int pos = atomicAdd(&cur[d], 1);
            if (pos < CAP) ebuf[(size_t)d * CAP + pos] = src[e];
        }
    }
}

// ---------- dinv from cursor counts ----------
__global__ void make_dinv_kernel(const int* __restrict__ cur, float* __restrict__ dinv, int n) {
    int i = blockIdx.x * blockDim.x + threadIdx.x;
    if (i < n) dinv[i] = rsqrtf((float)(cur[i] + 1));   // +1 self-loop
}

// ---------- GEMM1 (MFMA fp16): H1 = X (Mx512) @ W1 (512x64), fp16 out ----------
__global__ __launch_bounds__(256) void gemm1_mfma_kernel(const float* __restrict__ X,
                                                         const float* __restrict__ W,
                                                         __half* __restrict__ H, int M) {
    __shared__ _Float16 As[4][64][8];   // 4 KB
    __shared__ _Float16 Bs[4][64][8];   // 4 KB

    const int tid  = threadIdx.x;
    const int lane = tid & 63;
    const int w    = tid >> 6;
    const int l15  = lane & 15;
    const int kg   = lane >> 4;
    const int rowBase = blockIdx.x * 64;

    f32x4 acc[4] = {};

    for (int kt = 0; kt < F_IN; kt += 32) {
        #pragma unroll
        for (int p = 0; p < 2; ++p) {
            int idx = tid * 2 + p;           // 0..511
            int r = idx >> 3, k4 = idx & 7;  // row, k-quad
            int gr = rowBase + r; if (gr >= M) gr = M - 1;
            const float4 v = *reinterpret_cast<const float4*>(
                &X[(size_t)gr * F_IN + kt + k4 * 4]);
            _Float16* dstp = &As[k4 >> 1][r][(k4 & 1) * 4];
            dstp[0] = (_Float16)v.x; dstp[1] = (_Float16)v.y;
            dstp[2] = (_Float16)v.z; dstp[3] = (_Float16)v.w;
        }
        #pragma unroll
        for (int p = 0; p < 2; ++p) {
            int idx = tid * 2 + p;           // 0..511
            int k = idx >> 4, c4 = idx & 15;
            const float4 v = *reinterpret_cast<const float4*>(
                &W[(size_t)(kt + k) * HID + c4 * 4]);
            int kgg = k >> 3, j = k & 7;
            Bs[kgg][c4 * 4 + 0][j] = (_Float16)v.x;
            Bs[kgg][c4 * 4 + 1][j] = (_Float16)v.y;
            Bs[kgg][c4 * 4 + 2][j] = (_Float16)v.z;
            Bs[kgg][c4 * 4 + 3][j] = (_Float16)v.w;
        }
        __syncthreads();

        const half8 a = *reinterpret_cast<const half8*>(&As[kg][w * 16 + l15][0]);
        #pragma unroll
        for (int ct = 0; ct < 4; ++ct) {
            const half8 b = *reinterpret_cast<const half8*>(&Bs[kg][ct * 16 + l15][0]);
            acc[ct] = __builtin_amdgcn_mfma_f32_16x16x32_f16(a, b, acc[ct], 0, 0, 0);
        }
        __syncthreads();
    }

    #pragma unroll
    for (int ct = 0; ct < 4; ++ct) {
        #pragma unroll
        for (int r = 0; r < 4; ++r) {
            int grow = rowBase + w * 16 + kg * 4 + r;
            if (grow < M) H[(size_t)grow * HID + ct * 16 + l15] = __float2half(acc[ct][r]);
        }
    }
}

// ---------- agg1 + relu + b1 FUSED with gemm2 (block-parallel epilogue) ----------
// 4 waves = 4 nodes per block (grid exactly M/4 = 25000, M%4==0: no early return).
// Each wave gathers its node's z-row (one float/lane), writes it to LDS;
// after one barrier, threads 0..159 compute the 4x40 h2 = z @ W2 dots.
__global__ __launch_bounds__(256) void agg1_gemm2_kernel(const __half* __restrict__ h,
                                                         const int* __restrict__ ebuf,
                                                         const int* __restrict__ cur,
                                                         const float* __restrict__ dinv,
                                                         const float* __restrict__ b1,
                                                         const float* __restrict__ W2,
                                                         __half* __restrict__ h2) {
    __shared__ float W2s[HID * NCLS];   // 10.24 KB
    __shared__ float zt[4][HID];        // 1 KB

    const int tid  = threadIdx.x;
    const int lane = tid & 63;
    const int wv   = tid >> 6;
    const int n    = blockIdx.x * 4 + wv;

    for (int i = tid; i < HID * NCLS; i += 256) W2s[i] = W2[i];

    const float di = dinv[n];
    float acc = __half2float(h[(size_t)n * HID + lane]) * di * di;   // self-loop

    const int cnt = min(cur[n], CAP);
    const int* win = &ebuf[(size_t)n * CAP];

    int   s  = 0;
    float nm = 0.f;
    if (lane < cnt) {
        s  = win[lane];
        nm = dinv[s] * di;
    }
    int j = 0;
    for (; j + 4 <= cnt; j += 4) {
        int sa = __shfl(s, j);
        int sb = __shfl(s, j + 1);
        int sc = __shfl(s, j + 2);
        int sd = __shfl(s, j + 3);
        float na = __shfl(nm, j);
        float nb = __shfl(nm, j + 1);
        float nc = __shfl(nm, j + 2);
        float nd = __shfl(nm, j + 3);
        float va = __half2float(h[(size_t)sa * HID + lane]);
        float vb = __half2float(h[(size_t)sb * HID + lane]);
        float vc = __half2float(h[(size_t)sc * HID + lane]);
        float vd = __half2float(h[(size_t)sd * HID + lane]);
        acc = fmaf(va, na, acc);
        acc = fmaf(vb, nb, acc);
        acc = fmaf(vc, nc, acc);
        acc = fmaf(vd, nd, acc);
    }
    for (; j < cnt; ++j) {
        int sj = __shfl(s, j);
        float nj = __shfl(nm, j);
        acc = fmaf(__half2float(h[(size_t)sj * HID + lane]), nj, acc);
    }

    zt[wv][lane] = fmaxf(acc + b1[lane], 0.0f);   // z-row to LDS
    __syncthreads();

    if (tid < 4 * NCLS) {                          // 160 threads: one h2 element each
        int r = tid / NCLS, c = tid - r * NCLS;
        float sacc = 0.f;
        #pragma unroll
        for (int k = 0; k < HID; ++k)
            sacc = fmaf(zt[r][k], W2s[k * NCLS + c], sacc);
        h2[(size_t)(blockIdx.x * 4 + r) * 64 + c] = __float2half(sacc);  // stride 64
    }
}

// ---------- agg pass 2 + b2 + log_softmax; one wave per node, single batch ----------
__global__ __launch_bounds__(256) void agg2_lsm_kernel(const __half* __restrict__ h2,
                                                       const int* __restrict__ ebuf,
                                                       const int* __restrict__ cur,
                                                       const float* __restrict__ dinv,
                                                       const float* __restrict__ b2,
                                                       float* __restrict__ out, int M) {
    const int lane = threadIdx.x & 63;
    const int n = blockIdx.x * 4 + (threadIdx.x >> 6);
    if (n >= M) return;

    const bool act = (lane < NCLS);
    const float di = dinv[n];
    float acc = act ? __half2float(h2[(size_t)n * 64 + lane]) * di * di : 0.f;  // self-loop

    const int cnt = min(cur[n], CAP);
    const int* win = &ebuf[(size_t)n * CAP];

    int   s  = 0;
    float nm = 0.f;
    if (lane < cnt) {
        s  = win[lane];
        nm = dinv[s] * di;
    }
    int j = 0;
    for (; j + 4 <= cnt; j += 4) {
        int sa = __shfl(s, j);
        int sb = __shfl(s, j + 1);
        int sc = __shfl(s, j + 2);
        int sd = __shfl(s, j + 3);
        float na = __shfl(nm, j);
        float nb = __shfl(nm, j + 1);
        float nc = __shfl(nm, j + 2);
        float nd = __shfl(nm, j + 3);
        if (act) {
            float va = __half2float(h2[(size_t)sa * 64 + lane]);
            float vb = __half2float(h2[(size_t)sb * 64 + lane]);
            float vc = __half2float(h2[(size_t)sc * 64 + lane]);
            float vd = __half2float(h2[(size_t)sd * 64 + lane]);
            acc = fmaf(va, na, acc);
            acc = fmaf(vb, nb, acc);
            acc = fmaf(vc, nc, acc);
            acc = fmaf(vd, nd, acc);
        }
    }
    for (; j < cnt; ++j) {
        int sj = __shfl(s, j);
        float nj = __shfl(nm, j);
        if (act) acc = fmaf(__half2float(h2[(size_t)sj * 64 + lane]), nj, acc);
    }

    float logit = act ? (acc + b2[lane]) : -1e30f;
    float m = logit;
    #pragma unroll
    for (int o = 32; o >= 1; o >>= 1) m = fmaxf(m, __shfl_xor(m, o));
    float ex = act ? __expf(logit - m) : 0.f;
    float sm = ex;
    #pragma unroll
    for (int o = 32; o >= 1; o >>= 1) sm += __shfl_xor(sm, o);
    float res = logit - m - __logf(sm);

    if (act) out[(size_t)n * NCLS + lane] = res;
}

extern "C" void kernel_launch(void* const* d_in, const int* in_sizes, int n_in,
                              void* d_out, int out_size, void* d_ws, size_t ws_size,
                              hipStream_t stream) {
    const float* x  = (const float*)d_in[0];
    const int*   ei = (const int*)d_in[1];
    const float* W1 = (const float*)d_in[2];
    const float* b1 = (const float*)d_in[3];
    const float* W2 = (const float*)d_in[4];
    const float* b2 = (const float*)d_in[5];
    float* out = (float*)d_out;

    const int M = N_NODES;
    const int E = in_sizes[1] / 2;
    const int* src = ei;
    const int* dst = ei + E;

    // ---- workspace layout (peak ~52 MB; ws_size ≈ 800 MB per fill counters) ----
    char* ws = (char*)d_ws;
    int*    cur  = (int*)   (ws + 0);            // 400 KB (unpadded per-node cursors)
    float*  dinv = (float*) (ws + 409600);       // 400 KB
    int*    ebuf = (int*)   (ws + 819200);       // 100K * 64 * 4 B = 25.6 MB -> 26,419,200
    __half* h1   = (__half*)(ws + 26419200);     // 12.8 MB -> 39,219,200
    __half* h2   = (__half*)(ws + 39219200);     // stride-64: 12.8 MB -> 52,019,200

    zero_kernel<<<(M + 255) / 256, 256, 0, stream>>>(cur, M);

    scatter_part_kernel<<<NPART * PART_BLOCKS, 256, 0, stream>>>(src, dst, cur, ebuf, E);
    make_dinv_kernel<<<(M + 255) / 256, 256, 0, stream>>>(cur, dinv, M);

    gemm1_mfma_kernel<<<(M + 63) / 64, 256, 0, stream>>>(x, W1, h1, M);

    agg1_gemm2_kernel<<<M / 4, 256, 0, stream>>>(h1, ebuf, cur, dinv, b1, W2, h2);

    agg2_lsm_kernel<<<(M + 3) / 4, 256, 0, stream>>>(h2, ebuf, cur, dinv, b2, out, M);
}

// Round 15
// 294.573 us; speedup vs baseline: 1.3743x; 1.0009x over previous
//
#include <hip/hip_runtime.h>
#include <hip/hip_bf16.h>
#include <hip/hip_fp16.h>
#include <cstddef>

#define N_NODES 100000
#define F_IN    512
#define HID     64
#define NCLS    40

#define CAP       64                       // per-node window capacity (P(deg>64)~2e-18)

#define NPART        8
#define PART_NODES   12500                 // 100000/8
#define SCAT_BLOCKS  2048                  // 256 blocks per partition
#define GEMM1_BLOCKS 1563                  // ceil(100000/64)

using half8 = __attribute__((ext_vector_type(8))) _Float16;
using f32x4 = __attribute__((ext_vector_type(4))) float;

// ---------- utility ----------
__global__ void zero_kernel(int* __restrict__ p, int n) {
    int i = blockIdx.x * blockDim.x + threadIdx.x;
    if (i < n) p[i] = 0;
}

// ---------- FUSED: XCD-partitioned scatter (blocks 0..2047)  ||  GEMM1 MFMA (blocks 2048..) ----------
// scatter: partition p = blockIdx & 7 -> XCD p (round-robin dispatch); a node's
// window lines are written only from its partition's XCD -> lines fill in local L2.
// gemm1:   H1 = X (Mx512) @ W1 (512x64) -> fp16, 64x64 tile per block.
// The two halves have disjoint in/out sets; co-residency lets gemm1's MFMA/BW
// work fill scatter's atomic-latency stalls.
__global__ __launch_bounds__(256) void scatter_gemm1_kernel(const int* __restrict__ src,
                                                            const int* __restrict__ dst,
                                                            int* __restrict__ cur,
                                                            int* __restrict__ ebuf, int E,
                                                            const float* __restrict__ X,
                                                            const float* __restrict__ W,
                                                            __half* __restrict__ H, int M) {
    if (blockIdx.x < SCAT_BLOCKS) {
        // ---------------- scatter path ----------------
        const int p  = blockIdx.x & (NPART - 1);
        const int bi = blockIdx.x >> 3;                 // 0..255
        const int lo = p * PART_NODES, hi = lo + PART_NODES;
        for (int e = bi * 256 + (int)threadIdx.x; e < E; e += (SCAT_BLOCKS / NPART) * 256) {
            int d = dst[e];
            if (d >= lo && d < hi) {
                int pos = atomicAdd(&cur[d], 1);
                if (pos < CAP) ebuf[(size_t)d * CAP + pos] = src[e];
            }
        }
    } else {
        // ---------------- gemm1 path ----------------
        __shared__ _Float16 As[4][64][8];   // 4 KB
        __shared__ _Float16 Bs[4][64][8];   // 4 KB

        const int tid  = threadIdx.x;
        const int lane = tid & 63;
        const int w    = tid >> 6;
        const int l15  = lane & 15;
        const int kg   = lane >> 4;
        const int rowBase = (blockIdx.x - SCAT_BLOCKS) * 64;

        f32x4 acc[4] = {};

        for (int kt = 0; kt < F_IN; kt += 32) {
            #pragma unroll
            for (int p = 0; p < 2; ++p) {
                int idx = tid * 2 + p;           // 0..511
                int r = idx >> 3, k4 = idx & 7;  // row, k-quad
                int gr = rowBase + r; if (gr >= M) gr = M - 1;
                const float4 v = *reinterpret_cast<const float4*>(
                    &X[(size_t)gr * F_IN + kt + k4 * 4]);
                _Float16* dstp = &As[k4 >> 1][r][(k4 & 1) * 4];
                dstp[0] = (_Float16)v.x; dstp[1] = (_Float16)v.y;
                dstp[2] = (_Float16)v.z; dstp[3] = (_Float16)v.w;
            }
            #pragma unroll
            for (int p = 0; p < 2; ++p) {
                int idx = tid * 2 + p;           // 0..511
                int k = idx >> 4, c4 = idx & 15;
                const float4 v = *reinterpret_cast<const float4*>(
                    &W[(size_t)(kt + k) * HID + c4 * 4]);
                int kgg = k >> 3, j = k & 7;
                Bs[kgg][c4 * 4 + 0][j] = (_Float16)v.x;
                Bs[kgg][c4 * 4 + 1][j] = (_Float16)v.y;
                Bs[kgg][c4 * 4 + 2][j] = (_Float16)v.z;
                Bs[kgg][c4 * 4 + 3][j] = (_Float16)v.w;
            }
            __syncthreads();

            const half8 a = *reinterpret_cast<const half8*>(&As[kg][w * 16 + l15][0]);
            #pragma unroll
            for (int ct = 0; ct < 4; ++ct) {
                const half8 b = *reinterpret_cast<const half8*>(&Bs[kg][ct * 16 + l15][0]);
                acc[ct] = __builtin_amdgcn_mfma_f32_16x16x32_f16(a, b, acc[ct], 0, 0, 0);
            }
            __syncthreads();
        }

        #pragma unroll
        for (int ct = 0; ct < 4; ++ct) {
            #pragma unroll
            for (int r = 0; r < 4; ++r) {
                int grow = rowBase + w * 16 + kg * 4 + r;
                if (grow < M) H[(size_t)grow * HID + ct * 16 + l15] = __float2half(acc[ct][r]);
            }
        }
    }
}

// ---------- agg1 + relu + b1 FUSED with gemm2 (block-parallel epilogue) ----------
// 4 waves = 4 nodes per block (grid exactly M/4 = 25000, M%4==0: no early return).
// dinv computed on the fly: rsqrtf(cur[]+1). Each wave gathers its node's z-row,
// writes it to LDS; after one barrier, threads 0..159 do the 4x40 h2 dots.
__global__ __launch_bounds__(256) void agg1_gemm2_kernel(const __half* __restrict__ h,
                                                         const int* __restrict__ ebuf,
                                                         const int* __restrict__ cur,
                                                         const float* __restrict__ b1,
                                                         const float* __restrict__ W2,
                                                         __half* __restrict__ h2) {
    __shared__ float W2s[HID * NCLS];   // 10.24 KB
    __shared__ float zt[4][HID];        // 1 KB

    const int tid  = threadIdx.x;
    const int lane = tid & 63;
    const int wv   = tid >> 6;
    const int n    = blockIdx.x * 4 + wv;

    for (int i = tid; i < HID * NCLS; i += 256) W2s[i] = W2[i];

    const int cnt = min(cur[n], CAP);
    const float di = rsqrtf((float)(cnt + 1));
    float acc = __half2float(h[(size_t)n * HID + lane]) * di * di;   // self-loop

    const int* win = &ebuf[(size_t)n * CAP];

    int   s  = 0;
    float nm = 0.f;
    if (lane < cnt) {
        s  = win[lane];
        nm = rsqrtf((float)(min(cur[s], CAP) + 1)) * di;
    }
    int j = 0;
    for (; j + 4 <= cnt; j += 4) {
        int sa = __shfl(s, j);
        int sb = __shfl(s, j + 1);
        int sc = __shfl(s, j + 2);
        int sd = __shfl(s, j + 3);
        float na = __shfl(nm, j);
        float nb = __shfl(nm, j + 1);
        float nc = __shfl(nm, j + 2);
        float nd = __shfl(nm, j + 3);
        float va = __half2float(h[(size_t)sa * HID + lane]);
        float vb = __half2float(h[(size_t)sb * HID + lane]);
        float vc = __half2float(h[(size_t)sc * HID + lane]);
        float vd = __half2float(h[(size_t)sd * HID + lane]);
        acc = fmaf(va, na, acc);
        acc = fmaf(vb, nb, acc);
        acc = fmaf(vc, nc, acc);
        acc = fmaf(vd, nd, acc);
    }
    for (; j < cnt; ++j) {
        int sj = __shfl(s, j);
        float nj = __shfl(nm, j);
        acc = fmaf(__half2float(h[(size_t)sj * HID + lane]), nj, acc);
    }

    zt[wv][lane] = fmaxf(acc + b1[lane], 0.0f);   // z-row to LDS
    __syncthreads();

    if (tid < 4 * NCLS) {                          // 160 threads: one h2 element each
        int r = tid / NCLS, c = tid - r * NCLS;
        float sacc = 0.f;
        #pragma unroll
        for (int k = 0; k < HID; ++k)
            sacc = fmaf(zt[r][k], W2s[k * NCLS + c], sacc);
        h2[(size_t)(blockIdx.x * 4 + r) * 64 + c] = __float2half(sacc);  // stride 64
    }
}

// ---------- agg pass 2 + b2 + log_softmax; one wave per node, single batch ----------
__global__ __launch_bounds__(256) void agg2_lsm_kernel(const __half* __restrict__ h2,
                                                       const int* __restrict__ ebuf,
                                                       const int* __restrict__ cur,
                                                       const float* __restrict__ b2,
                                                       float* __restrict__ out, int M) {
    const int lane = threadIdx.x & 63;
    const int n = blockIdx.x * 4 + (threadIdx.x >> 6);
    if (n >= M) return;

    const bool act = (lane < NCLS);
    const int cnt = min(cur[n], CAP);
    const float di = rsqrtf((float)(cnt + 1));
    float acc = act ? __half2float(h2[(size_t)n * 64 + lane]) * di * di : 0.f;  // self-loop

    const int* win = &ebuf[(size_t)n * CAP];

    int   s  = 0;
    float nm = 0.f;
    if (lane < cnt) {
        s  = win[lane];
        nm = rsqrtf((float)(min(cur[s], CAP) + 1)) * di;
    }
    int j = 0;
    for (; j + 4 <= cnt; j += 4) {
        int sa = __shfl(s, j);
        int sb = __shfl(s, j + 1);
        int sc = __shfl(s, j + 2);
        int sd = __shfl(s, j + 3);
        float na = __shfl(nm, j);
        float nb = __shfl(nm, j + 1);
        float nc = __shfl(nm, j + 2);
        float nd = __shfl(nm, j + 3);
        if (act) {
            float va = __half2float(h2[(size_t)sa * 64 + lane]);
            float vb = __half2float(h2[(size_t)sb * 64 + lane]);
            float vc = __half2float(h2[(size_t)sc * 64 + lane]);
            float vd = __half2float(h2[(size_t)sd * 64 + lane]);
            acc = fmaf(va, na, acc);
            acc = fmaf(vb, nb, acc);
            acc = fmaf(vc, nc, acc);
            acc = fmaf(vd, nd, acc);
        }
    }
    for (; j < cnt; ++j) {
        int sj = __shfl(s, j);
        float nj = __shfl(nm, j);
        if (act) acc = fmaf(__half2float(h2[(size_t)sj * 64 + lane]), nj, acc);
    }

    float logit = act ? (acc + b2[lane]) : -1e30f;
    float m = logit;
    #pragma unroll
    for (int o = 32; o >= 1; o >>= 1) m = fmaxf(m, __shfl_xor(m, o));
    float ex = act ? __expf(logit - m) : 0.f;
    float sm = ex;
    #pragma unroll
    for (int o = 32; o >= 1; o >>= 1) sm += __shfl_xor(sm, o);
    float res = logit - m - __logf(sm);

    if (act) out[(size_t)n * NCLS + lane] = res;
}

extern "C" void kernel_launch(void* const* d_in, const int* in_sizes, int n_in,
                              void* d_out, int out_size, void* d_ws, size_t ws_size,
                              hipStream_t stream) {
    const float* x  = (const float*)d_in[0];
    const int*   ei = (const int*)d_in[1];
    const float* W1 = (const float*)d_in[2];
    const float* b1 = (const float*)d_in[3];
    const float* W2 = (const float*)d_in[4];
    const float* b2 = (const float*)d_in[5];
    float* out = (float*)d_out;

    const int M = N_NODES;
    const int E = in_sizes[1] / 2;
    const int* src = ei;
    const int* dst = ei + E;

    // ---- workspace layout (peak ~51.6 MB; ws_size ≈ 800 MB per fill counters) ----
    char* ws = (char*)d_ws;
    int*    cur  = (int*)   (ws + 0);            // 400 KB (per-node cursors; deg after scatter)
    int*    ebuf = (int*)   (ws + 409600);       // 100K * 64 * 4 B = 25.6 MB -> 26,009,600
    __half* h1   = (__half*)(ws + 26009600);     // 12.8 MB -> 38,809,600
    __half* h2   = (__half*)(ws + 38809600);     // stride-64: 12.8 MB -> 51,609,600

    zero_kernel<<<(M + 255) / 256, 256, 0, stream>>>(cur, M);

    scatter_gemm1_kernel<<<SCAT_BLOCKS + GEMM1_BLOCKS, 256, 0, stream>>>(
        src, dst, cur, ebuf, E, x, W1, h1, M);

    agg1_gemm2_kernel<<<M / 4, 256, 0, stream>>>(h1, ebuf, cur, b1, W2, h2);

    agg2_lsm_kernel<<<(M + 3) / 4, 256, 0, stream>>>(h2, ebuf, cur, b2, out, M);
}

// Round 16
// 294.445 us; speedup vs baseline: 1.3749x; 1.0004x over previous
//
#include <hip/hip_runtime.h>
#include <hip/hip_bf16.h>
#include <hip/hip_fp16.h>
#include <cstddef>

#define N_NODES 100000
#define F_IN    512
#define HID     64
#define NCLS    40

#define CAP       64                       // per-node window capacity (P(deg>64)~2e-18)

#define NPART        8
#define PART_NODES   12500                 // 100000/8
#define SCAT_BLOCKS  2048                  // 256 blocks per partition

using half8 = __attribute__((ext_vector_type(8))) _Float16;
using f32x4 = __attribute__((ext_vector_type(4))) float;

// ---------- utility ----------
__global__ void zero_kernel(int* __restrict__ p, int n) {
    int i = blockIdx.x * blockDim.x + threadIdx.x;
    if (i < n) p[i] = 0;
}

// ---------- XCD-partitioned scatter with NON-TEMPORAL edge-stream reads ----------
// partition p = blockIdx & 7 -> XCD p. The edge list (12.8 MB/scan) has zero
// reuse; nt loads keep it from evicting the ~1.4 MB of partially-filled window
// lines, so ebuf appends accumulate in L2 (16/line) instead of writing back
// one 64B line per 4B append.
__global__ __launch_bounds__(256) void scatter_part_kernel(const int* __restrict__ src,
                                                           const int* __restrict__ dst,
                                                           int* __restrict__ cur,
                                                           int* __restrict__ ebuf, int E) {
    const int p  = blockIdx.x & (NPART - 1);
    const int bi = blockIdx.x >> 3;
    const int lo = p * PART_NODES, hi = lo + PART_NODES;
    for (int e = bi * 256 + (int)threadIdx.x; e < E; e += (SCAT_BLOCKS / NPART) * 256) {
        int d = __builtin_nontemporal_load(&dst[e]);
        if (d >= lo && d < hi) {
            int s = __builtin_nontemporal_load(&src[e]);
            int pos = atomicAdd(&cur[d], 1);
            if (pos < CAP) ebuf[(size_t)d * CAP + pos] = s;
        }
    }
}

// ---------- GEMM1 (MFMA fp16): H1 = X (Mx512) @ W1 (512x64), fp16 out ----------
__global__ __launch_bounds__(256) void gemm1_mfma_kernel(const float* __restrict__ X,
                                                         const float* __restrict__ W,
                                                         __half* __restrict__ H, int M) {
    __shared__ _Float16 As[4][64][8];   // 4 KB
    __shared__ _Float16 Bs[4][64][8];   // 4 KB

    const int tid  = threadIdx.x;
    const int lane = tid & 63;
    const int w    = tid >> 6;
    const int l15  = lane & 15;
    const int kg   = lane >> 4;
    const int rowBase = blockIdx.x * 64;

    f32x4 acc[4] = {};

    for (int kt = 0; kt < F_IN; kt += 32) {
        #pragma unroll
        for (int p = 0; p < 2; ++p) {
            int idx = tid * 2 + p;           // 0..511
            int r = idx >> 3, k4 = idx & 7;  // row, k-quad
            int gr = rowBase + r; if (gr >= M) gr = M - 1;
            const float4 v = *reinterpret_cast<const float4*>(
                &X[(size_t)gr * F_IN + kt + k4 * 4]);
            _Float16* dstp = &As[k4 >> 1][r][(k4 & 1) * 4];
            dstp[0] = (_Float16)v.x; dstp[1] = (_Float16)v.y;
            dstp[2] = (_Float16)v.z; dstp[3] = (_Float16)v.w;
        }
        #pragma unroll
        for (int p = 0; p < 2; ++p) {
            int idx = tid * 2 + p;           // 0..511
            int k = idx >> 4, c4 = idx & 15;
            const float4 v = *reinterpret_cast<const float4*>(
                &W[(size_t)(kt + k) * HID + c4 * 4]);
            int kgg = k >> 3, j = k & 7;
            Bs[kgg][c4 * 4 + 0][j] = (_Float16)v.x;
            Bs[kgg][c4 * 4 + 1][j] = (_Float16)v.y;
            Bs[kgg][c4 * 4 + 2][j] = (_Float16)v.z;
            Bs[kgg][c4 * 4 + 3][j] = (_Float16)v.w;
        }
        __syncthreads();

        const half8 a = *reinterpret_cast<const half8*>(&As[kg][w * 16 + l15][0]);
        #pragma unroll
        for (int ct = 0; ct < 4; ++ct) {
            const half8 b = *reinterpret_cast<const half8*>(&Bs[kg][ct * 16 + l15][0]);
            acc[ct] = __builtin_amdgcn_mfma_f32_16x16x32_f16(a, b, acc[ct], 0, 0, 0);
        }
        __syncthreads();
    }

    #pragma unroll
    for (int ct = 0; ct < 4; ++ct) {
        #pragma unroll
        for (int r = 0; r < 4; ++r) {
            int grow = rowBase + w * 16 + kg * 4 + r;
            if (grow < M) H[(size_t)grow * HID + ct * 16 + l15] = __float2half(acc[ct][r]);
        }
    }
}

// ---------- agg1 + relu + b1 FUSED with gemm2 (block-parallel epilogue) ----------
// 4 waves = 4 nodes per block (grid exactly M/4 = 25000). dinv on the fly from
// cursor counts. Each wave gathers its node's z-row; threads 0..159 do 4x40 dots.
__global__ __launch_bounds__(256) void agg1_gemm2_kernel(const __half* __restrict__ h,
                                                         const int* __restrict__ ebuf,
                                                         const int* __restrict__ cur,
                                                         const float* __restrict__ b1,
                                                         const float* __restrict__ W2,
                                                         __half* __restrict__ h2) {
    __shared__ float W2s[HID * NCLS];   // 10.24 KB
    __shared__ float zt[4][HID];        // 1 KB

    const int tid  = threadIdx.x;
    const int lane = tid & 63;
    const int wv   = tid >> 6;
    const int n    = blockIdx.x * 4 + wv;

    for (int i = tid; i < HID * NCLS; i += 256) W2s[i] = W2[i];

    const int deg = cur[n];
    const int cnt = min(deg, CAP);
    const float di = rsqrtf((float)(deg + 1));
    float acc = __half2float(h[(size_t)n * HID + lane]) * di * di;   // self-loop

    const int* win = &ebuf[(size_t)n * CAP];

    int   s  = 0;
    float nm = 0.f;
    if (lane < cnt) {
        s  = win[lane];
        nm = rsqrtf((float)(cur[s] + 1)) * di;
    }
    int j = 0;
    for (; j + 4 <= cnt; j += 4) {
        int sa = __shfl(s, j);
        int sb = __shfl(s, j + 1);
        int sc = __shfl(s, j + 2);
        int sd = __shfl(s, j + 3);
        float na = __shfl(nm, j);
        float nb = __shfl(nm, j + 1);
        float nc = __shfl(nm, j + 2);
        float nd = __shfl(nm, j + 3);
        float va = __half2float(h[(size_t)sa * HID + lane]);
        float vb = __half2float(h[(size_t)sb * HID + lane]);
        float vc = __half2float(h[(size_t)sc * HID + lane]);
        float vd = __half2float(h[(size_t)sd * HID + lane]);
        acc = fmaf(va, na, acc);
        acc = fmaf(vb, nb, acc);
        acc = fmaf(vc, nc, acc);
        acc = fmaf(vd, nd, acc);
    }
    for (; j < cnt; ++j) {
        int sj = __shfl(s, j);
        float nj = __shfl(nm, j);
        acc = fmaf(__half2float(h[(size_t)sj * HID + lane]), nj, acc);
    }

    zt[wv][lane] = fmaxf(acc + b1[lane], 0.0f);   // z-row to LDS
    __syncthreads();

    if (tid < 4 * NCLS) {                          // 160 threads: one h2 element each
        int r = tid / NCLS, c = tid - r * NCLS;
        float sacc = 0.f;
        #pragma unroll
        for (int k = 0; k < HID; ++k)
            sacc = fmaf(zt[r][k], W2s[k * NCLS + c], sacc);
        h2[(size_t)(blockIdx.x * 4 + r) * 64 + c] = __float2half(sacc);  // stride 64
    }
}

// ---------- agg pass 2 + b2 + log_softmax; one wave per node, single batch ----------
__global__ __launch_bounds__(256) void agg2_lsm_kernel(const __half* __restrict__ h2,
                                                       const int* __restrict__ ebuf,
                                                       const int* __restrict__ cur,
                                                       const float* __restrict__ b2,
                                                       float* __restrict__ out, int M) {
    const int lane = threadIdx.x & 63;
    const int n = blockIdx.x * 4 + (threadIdx.x >> 6);
    if (n >= M) return;

    const bool act = (lane < NCLS);
    const int deg = cur[n];
    const int cnt = min(deg, CAP);
    const float di = rsqrtf((float)(deg + 1));
    float acc = act ? __half2float(h2[(size_t)n * 64 + lane]) * di * di : 0.f;  // self-loop

    const int* win = &ebuf[(size_t)n * CAP];

    int   s  = 0;
    float nm = 0.f;
    if (lane < cnt) {
        s  = win[lane];
        nm = rsqrtf((float)(cur[s] + 1)) * di;
    }
    int j = 0;
    for (; j + 4 <= cnt; j += 4) {
        int sa = __shfl(s, j);
        int sb = __shfl(s, j + 1);
        int sc = __shfl(s, j + 2);
        int sd = __shfl(s, j + 3);
        float na = __shfl(nm, j);
        float nb = __shfl(nm, j + 1);
        float nc = __shfl(nm, j + 2);
        float nd = __shfl(nm, j + 3);
        if (act) {
            float va = __half2float(h2[(size_t)sa * 64 + lane]);
            float vb = __half2float(h2[(size_t)sb * 64 + lane]);
            float vc = __half2float(h2[(size_t)sc * 64 + lane]);
            float vd = __half2float(h2[(size_t)sd * 64 + lane]);
            acc = fmaf(va, na, acc);
            acc = fmaf(vb, nb, acc);
            acc = fmaf(vc, nc, acc);
            acc = fmaf(vd, nd, acc);
        }
    }
    for (; j < cnt; ++j) {
        int sj = __shfl(s, j);
        float nj = __shfl(nm, j);
        if (act) acc = fmaf(__half2float(h2[(size_t)sj * 64 + lane]), nj, acc);
    }

    float logit = act ? (acc + b2[lane]) : -1e30f;
    float m = logit;
    #pragma unroll
    for (int o = 32; o >= 1; o >>= 1) m = fmaxf(m, __shfl_xor(m, o));
    float ex = act ? __expf(logit - m) : 0.f;
    float sm = ex;
    #pragma unroll
    for (int o = 32; o >= 1; o >>= 1) sm += __shfl_xor(sm, o);
    float res = logit - m - __logf(sm);

    if (act) out[(size_t)n * NCLS + lane] = res;
}

extern "C" void kernel_launch(void* const* d_in, const int* in_sizes, int n_in,
                              void* d_out, int out_size, void* d_ws, size_t ws_size,
                              hipStream_t stream) {
    const float* x  = (const float*)d_in[0];
    const int*   ei = (const int*)d_in[1];
    const float* W1 = (const float*)d_in[2];
    const float* b1 = (const float*)d_in[3];
    const float* W2 = (const float*)d_in[4];
    const float* b2 = (const float*)d_in[5];
    float* out = (float*)d_out;

    const int M = N_NODES;
    const int E = in_sizes[1] / 2;
    const int* src = ei;
    const int* dst = ei + E;

    // ---- workspace layout (peak ~51.6 MB; ws_size ≈ 800 MB per fill counters) ----
    char* ws = (char*)d_ws;
    int*    cur  = (int*)   (ws + 0);            // 400 KB (per-node cursors = degree)
    int*    ebuf = (int*)   (ws + 409600);       // 100K * 64 * 4 B = 25.6 MB -> 26,009,600
    __half* h1   = (__half*)(ws + 26009600);     // 12.8 MB -> 38,809,600
    __half* h2   = (__half*)(ws + 38809600);     // stride-64: 12.8 MB -> 51,609,600

    zero_kernel<<<(M + 255) / 256, 256, 0, stream>>>(cur, M);

    scatter_part_kernel<<<SCAT_BLOCKS, 256, 0, stream>>>(src, dst, cur, ebuf, E);

    gemm1_mfma_kernel<<<(M + 63) / 64, 256, 0, stream>>>(x, W1, h1, M);

    agg1_gemm2_kernel<<<M / 4, 256, 0, stream>>>(h1, ebuf, cur, b1, W2, h2);

    agg2_lsm_kernel<<<(M + 3) / 4, 256, 0, stream>>>(h2, ebuf, cur, b2, out, M);
}